// Round 10
// baseline (469.505 us; speedup 1.0000x reference)
//
#include <hip/hip_runtime.h>

#define NN 100000
#define NE 1600000
#define C 32

#define SHIFT 7
#define BINW 128                              // nodes per bin
#define NBIN ((NN + BINW - 1) / BINW)         // 782
#define EPB2 8192                             // edges per block (binning)
#define NBLK2 ((NE + EPB2 - 1) / EPB2)        // 196
#define VTOT (NBIN * NBLK2)                   // 153272 (bin-major cmat scan)
#define VTILE 4096
#define NVT ((VTOT + VTILE - 1) / VTILE)      // 38 (<=64: one-wave scan)

__device__ __forceinline__ unsigned bf16rne(float f) {
    unsigned u = __float_as_uint(f);
    return (u + 0x7fffu + ((u >> 16) & 1u)) >> 16;
}

// ---------------- kernels ----------------

// per-block coarse-bin histogram (LDS only; no global atomics)
__global__ __launch_bounds__(256) void k_histB(const int* __restrict__ ei,
                                               int* __restrict__ cmat) {
    __shared__ int lh[NBIN];
    for (int i = threadIdx.x; i < NBIN; i += 256) lh[i] = 0;
    __syncthreads();
    int b = blockIdx.x;
    int e0 = b * EPB2, e1 = min(e0 + EPB2, NE);
    for (int e = e0 + threadIdx.x; e < e1; e += 256)
        atomicAdd(&lh[ei[NE + e] >> SHIFT], 1);
    __syncthreads();
    for (int i = threadIdx.x; i < NBIN; i += 256)
        cmat[b * NBIN + i] = lh[i];
}

// ---- cmat scan (bin-major virtual order) -> gbase ----

__global__ __launch_bounds__(256) void k_psumC(const int* __restrict__ cmat,
                                               int* __restrict__ bsum2) {
    int base = blockIdx.x * VTILE;
    int s = 0;
    for (int i = threadIdx.x; i < VTILE; i += 256) {
        int v = base + i;
        if (v < VTOT) {
            int bin = v / NBLK2, blk = v - bin * NBLK2;
            s += cmat[blk * NBIN + bin];
        }
    }
#pragma unroll
    for (int d = 32; d; d >>= 1) s += __shfl_down(s, d);
    __shared__ int wsum[4];
    if ((threadIdx.x & 63) == 0) wsum[threadIdx.x >> 6] = s;
    __syncthreads();
    if (threadIdx.x == 0) bsum2[blockIdx.x] = wsum[0] + wsum[1] + wsum[2] + wsum[3];
}

// tile-local scan + inline one-wave scan of the 38 tile sums
__global__ __launch_bounds__(256) void k_finC(const int* __restrict__ cmat,
                                              const int* __restrict__ bsum2,
                                              int* __restrict__ gbase) {
    __shared__ int ts[256];
    __shared__ int sboff;
    int t = threadIdx.x;
    if (t < 64) {                         // inline bscan (NVT<=64)
        int orig = (t < NVT) ? bsum2[t] : 0;
        int v = orig;
#pragma unroll
        for (int d = 1; d < 64; d <<= 1) {
            int u = __shfl_up(v, d);
            if (t >= d) v += u;
        }
        if (t == blockIdx.x) sboff = v - orig;
    }
    int s0 = blockIdx.x * VTILE + t * 16;
    int v[16];
    int sum = 0;
#pragma unroll
    for (int k = 0; k < 16; ++k) {
        int idx = s0 + k;
        if (idx < VTOT) {
            int bin = idx / NBLK2, blk = idx - bin * NBLK2;
            v[k] = cmat[blk * NBIN + bin];
        } else v[k] = 0;
        sum += v[k];
    }
    ts[t] = sum;
    __syncthreads();
    for (int d = 1; d < 256; d <<= 1) {
        int u = (t >= d) ? ts[t - d] : 0;
        __syncthreads();
        ts[t] += u;
        __syncthreads();
    }
    int run = sboff + ts[t] - sum;
#pragma unroll
    for (int k = 0; k < 16; ++k) {
        int idx = s0 + k;
        if (idx < VTOT) gbase[idx] = run;   // bin-major, coalesced
        run += v[k];
    }
}

// deterministic scatter into coarse bins (LDS cursors from gbase)
__global__ __launch_bounds__(256) void k_binD(const int* __restrict__ ei,
                                              const int* __restrict__ gbase,
                                              int* __restrict__ tmp) {
    __shared__ int lcur[NBIN];
    int b = blockIdx.x;
    for (int i = threadIdx.x; i < NBIN; i += 256)
        lcur[i] = gbase[i * NBLK2 + b];
    __syncthreads();
    int e0 = b * EPB2, e1 = min(e0 + EPB2, NE);
    for (int e = e0 + threadIdx.x; e < e1; e += 256) {
        int src = ei[e], cl = ei[NE + e];
        int pos = atomicAdd(&lcur[cl >> SHIFT], 1);   // LDS atomic: cheap
        tmp[pos] = (src << SHIFT) | (cl & (BINW - 1));
    }
}

// per-bin node degree -> dinv (slice histogram; no scan, no CSR)
__global__ __launch_bounds__(256) void k_deg(const int* __restrict__ gbase,
                                             const int* __restrict__ tmp,
                                             float* __restrict__ dinv) {
    __shared__ int lcnt[BINW];
    int bin = blockIdx.x, t = threadIdx.x;
    if (t < BINW) lcnt[t] = 0;
    __syncthreads();
    int s0 = gbase[bin * NBLK2];
    int s1 = (bin + 1 < NBIN) ? gbase[(bin + 1) * NBLK2] : NE;
    for (int i = s0 + t; i < s1; i += 256)
        atomicAdd(&lcnt[tmp[i] & (BINW - 1)], 1);
    __syncthreads();
    if (t < BINW) {
        int node = (bin << SHIFT) + t;
        if (node < NN) dinv[node] = rsqrtf(1.0f + (float)lcnt[t]);
    }
}

// h' = bf16( dinv * (x @ W^T) ), packed 2 channels/uint -> 64B rows.
__global__ __launch_bounds__(256) void k_linear(const float* __restrict__ x,
                                                const float* __restrict__ W,
                                                const float* __restrict__ dinv,
                                                unsigned* __restrict__ hu) {
    __shared__ float Ws[C][C + 1];
    __shared__ float xs[16][C];
    int t = threadIdx.x;
    for (int i = t; i < C * C; i += 256)
        Ws[i / C][i % C] = W[i];

    int node0 = blockIdx.x * 16;
#pragma unroll
    for (int i = t; i < 16 * C; i += 256) {
        int idx = node0 * C + i;     // coalesced load of 16 rows
        xs[i >> 5][i & 31] = (idx < NN * C) ? x[idx] : 0.0f;
    }
    __syncthreads();
    int lnode = t >> 4, m = t & 15;
    int node = node0 + lnode;
    if (node < NN) {
        float a0 = 0.0f, a1 = 0.0f;
#pragma unroll
        for (int k = 0; k < C; ++k) {
            float xv = xs[lnode][k];
            a0 += xv * Ws[2 * m][k];
            a1 += xv * Ws[2 * m + 1][k];
        }
        float d = dinv[node];
        hu[node * 16 + m] = bf16rne(a0 * d) | (bf16rne(a1 * d) << 16);
    }
}

// one block per bin: stream slice, gather hu rows (64B, quarter-wave),
// accumulate into LDS f32 acc via ds_add_f32; single coalesced row store.
__global__ __launch_bounds__(256) void k_aggF(const int* __restrict__ gbase,
                                              const int* __restrict__ tmp,
                                              const unsigned* __restrict__ hu,
                                              const float* __restrict__ dinv,
                                              const float* __restrict__ b,
                                              float* __restrict__ out) {
    __shared__ float acc[BINW * C];          // 16 KB
    int bin = blockIdx.x, t = threadIdx.x;
    for (int i = t; i < BINW * C; i += 256) acc[i] = 0.0f;
    __syncthreads();
    int s0 = gbase[bin * NBLK2];
    int s1 = (bin + 1 < NBIN) ? gbase[(bin + 1) * NBLK2] : NE;
    int slot = t >> 4, m = t & 15;           // 16 slots x 16 lanes
    for (int i = s0 + slot; i < s1; i += 16) {
        int v = tmp[i];                      // broadcast within quarter-wave
        int src = v >> SHIFT, cn = v & (BINW - 1);
        unsigned u = hu[src * 16 + m];       // 64B coalesced row gather
        atomicAdd(&acc[cn * C + 2 * m],     __uint_as_float(u << 16));
        atomicAdd(&acc[cn * C + 2 * m + 1], __uint_as_float(u & 0xffff0000u));
    }
    __syncthreads();
    float b0 = b[2 * m], b1 = b[2 * m + 1];
    for (int n0 = slot; n0 < BINW; n0 += 16) {
        int n = (bin << SHIFT) + n0;
        if (n >= NN) break;
        float dn = dinv[n];
        unsigned us = hu[n * 16 + m];        // self-loop row (pre-scaled)
        float ox = b0 + dn * (acc[n0 * C + 2 * m]     + __uint_as_float(us << 16));
        float oy = b1 + dn * (acc[n0 * C + 2 * m + 1] + __uint_as_float(us & 0xffff0000u));
        ((float2*)out)[n * 16 + m] = make_float2(ox, oy);
    }
}

// ---------------- launch ----------------

extern "C" void kernel_launch(void* const* d_in, const int* in_sizes, int n_in,
                              void* d_out, int out_size, void* d_ws, size_t ws_size,
                              hipStream_t stream) {
    const float* x  = (const float*)d_in[0];
    const int*   ei = (const int*)d_in[1];
    const float* W  = (const float*)d_in[2];
    const float* b  = (const float*)d_in[3];
    float* out = (float*)d_out;

    // ws (~15 MB of the 256 MB pool) — no overlays, all buffers distinct
    char* ws = (char*)d_ws;
    size_t o = 0;
    int*      tmp  = (int*)(ws + o);      o += (size_t)NE * 4;        o = (o + 255) & ~(size_t)255;
    unsigned* hu   = (unsigned*)(ws + o); o += (size_t)NN * 16 * 4;   o = (o + 255) & ~(size_t)255;
    int*      cmat = (int*)(ws + o);      o += (size_t)VTOT * 4;      o = (o + 255) & ~(size_t)255;
    int*      gbase= (int*)(ws + o);      o += (size_t)VTOT * 4;      o = (o + 255) & ~(size_t)255;
    float*    dinv = (float*)(ws + o);    o += (size_t)NN * 4;        o = (o + 255) & ~(size_t)255;
    int*      bsum2= (int*)(ws + o);

    k_histB<<<NBLK2, 256, 0, stream>>>(ei, cmat);
    k_psumC<<<NVT, 256, 0, stream>>>(cmat, bsum2);
    k_finC<<<NVT, 256, 0, stream>>>(cmat, bsum2, gbase);
    k_binD<<<NBLK2, 256, 0, stream>>>(ei, gbase, tmp);
    k_deg<<<NBIN, 256, 0, stream>>>(gbase, tmp, dinv);
    k_linear<<<(NN + 15) / 16, 256, 0, stream>>>(x, W, dinv, hu);
    k_aggF<<<NBIN, 256, 0, stream>>>(gbase, tmp, hu, dinv, b, out);
}

// Round 11
// 177.983 us; speedup vs baseline: 2.6379x; 2.6379x over previous
//
#include <hip/hip_runtime.h>

#define NN 100000
#define NE 1600000
#define C 32

#define SHIFT 8
#define BINW 256                              // nodes per bin
#define NBIN ((NN + BINW - 1) / BINW)         // 391
#define EPB2 8192                             // edges per block (binning)
#define NBLK2 ((NE + EPB2 - 1) / EPB2)        // 196
#define VTOT (NBIN * NBLK2)                   // 76636 (bin-major cmat scan)
#define VTILE 2048
#define NVT ((VTOT + VTILE - 1) / VTILE)      // 38 (<=64: one-wave scan)

__device__ __forceinline__ unsigned bf16rne(float f) {
    unsigned u = __float_as_uint(f);
    return (u + 0x7fffu + ((u >> 16) & 1u)) >> 16;
}

// ---------------- kernels ----------------

// per-block coarse-bin histogram (LDS only; no global atomics)
__global__ __launch_bounds__(256) void k_histB(const int* __restrict__ ei,
                                               int* __restrict__ cmat) {
    __shared__ int lh[NBIN];
    for (int i = threadIdx.x; i < NBIN; i += 256) lh[i] = 0;
    __syncthreads();
    int b = blockIdx.x;
    int e0 = b * EPB2, e1 = min(e0 + EPB2, NE);
    for (int e = e0 + threadIdx.x; e < e1; e += 256)
        atomicAdd(&lh[ei[NE + e] >> SHIFT], 1);
    __syncthreads();
    for (int i = threadIdx.x; i < NBIN; i += 256)
        cmat[b * NBIN + i] = lh[i];
}

// ---- cmat scan (bin-major virtual order) -> gbase ----

__global__ __launch_bounds__(256) void k_psumC(const int* __restrict__ cmat,
                                               int* __restrict__ bsum2) {
    int base = blockIdx.x * VTILE;
    int s = 0;
    for (int i = threadIdx.x; i < VTILE; i += 256) {
        int v = base + i;
        if (v < VTOT) {
            int bin = v / NBLK2, blk = v - bin * NBLK2;
            s += cmat[blk * NBIN + bin];
        }
    }
#pragma unroll
    for (int d = 32; d; d >>= 1) s += __shfl_down(s, d);
    __shared__ int wsum[4];
    if ((threadIdx.x & 63) == 0) wsum[threadIdx.x >> 6] = s;
    __syncthreads();
    if (threadIdx.x == 0) bsum2[blockIdx.x] = wsum[0] + wsum[1] + wsum[2] + wsum[3];
}

// tile-local scan + inline one-wave scan of the NVT tile sums
__global__ __launch_bounds__(256) void k_finC(const int* __restrict__ cmat,
                                              const int* __restrict__ bsum2,
                                              int* __restrict__ gbase) {
    __shared__ int ts[256];
    __shared__ int sboff;
    int t = threadIdx.x;
    if (t < 64) {                         // inline bscan (NVT<=64)
        int orig = (t < NVT) ? bsum2[t] : 0;
        int v = orig;
#pragma unroll
        for (int d = 1; d < 64; d <<= 1) {
            int u = __shfl_up(v, d);
            if (t >= d) v += u;
        }
        if (t == blockIdx.x) sboff = v - orig;
    }
    int s0 = blockIdx.x * VTILE + t * 8;
    int v[8];
    int sum = 0;
#pragma unroll
    for (int k = 0; k < 8; ++k) {
        int idx = s0 + k;
        if (idx < VTOT) {
            int bin = idx / NBLK2, blk = idx - bin * NBLK2;
            v[k] = cmat[blk * NBIN + bin];
        } else v[k] = 0;
        sum += v[k];
    }
    ts[t] = sum;
    __syncthreads();
    for (int d = 1; d < 256; d <<= 1) {
        int u = (t >= d) ? ts[t - d] : 0;
        __syncthreads();
        ts[t] += u;
        __syncthreads();
    }
    int run = sboff + ts[t] - sum;
#pragma unroll
    for (int k = 0; k < 8; ++k) {
        int idx = s0 + k;
        if (idx < VTOT) gbase[idx] = run;   // bin-major, coalesced
        run += v[k];
    }
}

// deterministic scatter into coarse bins (LDS cursors from gbase)
__global__ __launch_bounds__(256) void k_binD(const int* __restrict__ ei,
                                              const int* __restrict__ gbase,
                                              int* __restrict__ tmp) {
    __shared__ int lcur[NBIN];
    int b = blockIdx.x;
    for (int i = threadIdx.x; i < NBIN; i += 256)
        lcur[i] = gbase[i * NBLK2 + b];
    __syncthreads();
    int e0 = b * EPB2, e1 = min(e0 + EPB2, NE);
    for (int e = e0 + threadIdx.x; e < e1; e += 256) {
        int src = ei[e], cl = ei[NE + e];
        int pos = atomicAdd(&lcur[cl >> SHIFT], 1);   // LDS atomic: cheap
        tmp[pos] = (src << SHIFT) | (cl & (BINW - 1));
    }
}

// one block per bin: LDS node-histogram of the bin slice -> off/dinv,
// then exact CSR placement. Zero global atomics anywhere.
__global__ __launch_bounds__(256) void k_placeB(const int* __restrict__ gbase,
                                                const int* __restrict__ tmp,
                                                int* __restrict__ srt,
                                                int* __restrict__ off,
                                                float* __restrict__ dinv) {
    __shared__ int lcnt[BINW];
    __shared__ int ts[BINW];
    __shared__ int lcur[BINW];
    int bin = blockIdx.x, t = threadIdx.x;
    int s0 = gbase[bin * NBLK2];
    int s1 = (bin + 1 < NBIN) ? gbase[(bin + 1) * NBLK2] : NE;
    lcnt[t] = 0;
    __syncthreads();
    for (int i = s0 + t; i < s1; i += 256)
        atomicAdd(&lcnt[tmp[i] & (BINW - 1)], 1);
    __syncthreads();
    int cv = lcnt[t];
    ts[t] = cv;
    __syncthreads();
    for (int d = 1; d < 256; d <<= 1) {   // Hillis-Steele inclusive
        int u = (t >= d) ? ts[t - d] : 0;
        __syncthreads();
        ts[t] += u;
        __syncthreads();
    }
    int base = s0 + ts[t] - cv;           // exclusive node offset
    lcur[t] = base;
    int node = (bin << SHIFT) + t;
    if (node < NN) {
        off[node] = base;
        dinv[node] = rsqrtf(1.0f + (float)cv);   // deg incl. self-loop
        if (node == NN - 1) off[NN] = NE;
    }
    __syncthreads();
    for (int i = s0 + t; i < s1; i += 256) {
        int v = tmp[i];
        int pos = atomicAdd(&lcur[v & (BINW - 1)], 1);
        srt[pos] = v >> SHIFT;
    }
}

// h' = bf16( dinv * (x @ W^T) ), packed 2 channels/uint -> 64B rows.
// 256 thr = 16 nodes x 16 lanes; each lane computes channels 2m,2m+1.
__global__ __launch_bounds__(256) void k_linear(const float* __restrict__ x,
                                                const float* __restrict__ W,
                                                const float* __restrict__ dinv,
                                                unsigned* __restrict__ hu) {
    __shared__ float Ws[C][C + 1];
    __shared__ float xs[16][C];
    int t = threadIdx.x;
    for (int i = t; i < C * C; i += 256)
        Ws[i / C][i % C] = W[i];

    int node0 = blockIdx.x * 16;
#pragma unroll
    for (int i = t; i < 16 * C; i += 256) {
        int idx = node0 * C + i;     // coalesced load of 16 rows
        xs[i >> 5][i & 31] = (idx < NN * C) ? x[idx] : 0.0f;
    }
    __syncthreads();
    int lnode = t >> 4, m = t & 15;
    int node = node0 + lnode;
    if (node < NN) {
        float a0 = 0.0f, a1 = 0.0f;
#pragma unroll
        for (int k = 0; k < C; ++k) {
            float xv = xs[lnode][k];
            a0 += xv * Ws[2 * m][k];
            a1 += xv * Ws[2 * m + 1][k];
        }
        float d = dinv[node];
        hu[node * 16 + m] = bf16rne(a0 * d) | (bf16rne(a1 * d) << 16);
    }
}

// one 64-lane wave per node; 16-lane quarter-wave per edge row (64B = 1
// line), 4 edges/iter, 2x unrolled. out = b + dn*(sum h'[r] + h'[n]).
__global__ __launch_bounds__(256) void k_agg(const int* __restrict__ off,
                                             const int* __restrict__ srt,
                                             const unsigned* __restrict__ hu,
                                             const float* __restrict__ dinv,
                                             const float* __restrict__ b,
                                             float* __restrict__ out) {
    int n = (blockIdx.x * blockDim.x + threadIdx.x) >> 6;
    if (n >= NN) return;
    int lane = threadIdx.x & 63;
    int q = lane >> 4, m = lane & 15;    // slot q handles edges j%4==q
    int beg = off[n], end = off[n + 1];
    float sx = 0.0f, sy = 0.0f, sx2 = 0.0f, sy2 = 0.0f;
    int j = beg + q;
    for (; j + 4 < end; j += 8) {
        int r0 = srt[j], r1 = srt[j + 4];
        unsigned u0 = hu[r0 * 16 + m];
        unsigned u1 = hu[r1 * 16 + m];
        sx  += __uint_as_float(u0 << 16);
        sy  += __uint_as_float(u0 & 0xffff0000u);
        sx2 += __uint_as_float(u1 << 16);
        sy2 += __uint_as_float(u1 & 0xffff0000u);
    }
    for (; j < end; j += 4) {
        unsigned u = hu[srt[j] * 16 + m];
        sx += __uint_as_float(u << 16);
        sy += __uint_as_float(u & 0xffff0000u);
    }
    sx += sx2; sy += sy2;
    sx += __shfl_xor(sx, 16); sy += __shfl_xor(sy, 16);
    sx += __shfl_xor(sx, 32); sy += __shfl_xor(sy, 32);
    if (q == 0) {
        float dn = dinv[n];
        unsigned us = hu[n * 16 + m];    // self-loop row (pre-scaled)
        float ox = b[2 * m]     + dn * (sx + __uint_as_float(us << 16));
        float oy = b[2 * m + 1] + dn * (sy + __uint_as_float(us & 0xffff0000u));
        ((float2*)out)[n * 16 + m] = make_float2(ox, oy);
    }
}

// ---------------- launch ----------------

extern "C" void kernel_launch(void* const* d_in, const int* in_sizes, int n_in,
                              void* d_out, int out_size, void* d_ws, size_t ws_size,
                              hipStream_t stream) {
    const float* x  = (const float*)d_in[0];
    const int*   ei = (const int*)d_in[1];
    const float* W  = (const float*)d_in[2];
    const float* b  = (const float*)d_in[3];
    float* out = (float*)d_out;

    // ws (~21 MB of 256 MB pool) — no overlays, all buffers distinct
    char* ws = (char*)d_ws;
    size_t o = 0;
    int*      tmp  = (int*)(ws + o);      o += (size_t)NE * 4;        o = (o + 255) & ~(size_t)255;
    int*      srt  = (int*)(ws + o);      o += (size_t)NE * 4;        o = (o + 255) & ~(size_t)255;
    unsigned* hu   = (unsigned*)(ws + o); o += (size_t)NN * 16 * 4;   o = (o + 255) & ~(size_t)255;
    int*      cmat = (int*)(ws + o);      o += (size_t)VTOT * 4;      o = (o + 255) & ~(size_t)255;
    int*      gbase= (int*)(ws + o);      o += (size_t)VTOT * 4;      o = (o + 255) & ~(size_t)255;
    int*      off  = (int*)(ws + o);      o += (size_t)(NN + 1) * 4;  o = (o + 255) & ~(size_t)255;
    float*    dinv = (float*)(ws + o);    o += (size_t)NN * 4;        o = (o + 255) & ~(size_t)255;
    int*      bsum2= (int*)(ws + o);

    k_histB<<<NBLK2, 256, 0, stream>>>(ei, cmat);
    k_psumC<<<NVT, 256, 0, stream>>>(cmat, bsum2);
    k_finC<<<NVT, 256, 0, stream>>>(cmat, bsum2, gbase);
    k_binD<<<NBLK2, 256, 0, stream>>>(ei, gbase, tmp);
    k_placeB<<<NBIN, 256, 0, stream>>>(gbase, tmp, srt, off, dinv);
    k_linear<<<(NN + 15) / 16, 256, 0, stream>>>(x, W, dinv, hu);
    k_agg<<<(NN * 64 + 255) / 256, 256, 0, stream>>>(off, srt, hu, dinv, b, out);
}

// Round 12
// 165.308 us; speedup vs baseline: 2.8402x; 1.0767x over previous
//
#include <hip/hip_runtime.h>

#define NN 100000
#define NE 1600000
#define C 32

#define SHIFT 8
#define BINW 256                              // nodes per bin
#define NBIN ((NN + BINW - 1) / BINW)         // 391
#define EPB2 8192                             // edges per block (binning)
#define NBLK2 ((NE + EPB2 - 1) / EPB2)        // 196
#define VTOT (NBIN * NBLK2)                   // 76636 (bin-major cmat scan)
#define VTILE 2048
#define NVT ((VTOT + VTILE - 1) / VTILE)      // 38 (<=64: one-wave scan)
#define PCAP 5376                             // placeB LDS stash entries (20σ)

__device__ __forceinline__ unsigned bf16rne(float f) {
    unsigned u = __float_as_uint(f);
    return (u + 0x7fffu + ((u >> 16) & 1u)) >> 16;
}

// ---------------- kernels ----------------

// per-block coarse-bin histogram (LDS only; int4 edge loads)
__global__ __launch_bounds__(256) void k_histB(const int* __restrict__ ei,
                                               int* __restrict__ cmat) {
    __shared__ int lh[NBIN];
    for (int i = threadIdx.x; i < NBIN; i += 256) lh[i] = 0;
    __syncthreads();
    int b = blockIdx.x;
    int e0 = b * EPB2, e1 = min(e0 + EPB2, NE);   // window always %4==0
    const int4* col4 = (const int4*)(ei + NE);
    for (int q = (e0 >> 2) + threadIdx.x; q < (e1 >> 2); q += 256) {
        int4 c = col4[q];
        atomicAdd(&lh[c.x >> SHIFT], 1);
        atomicAdd(&lh[c.y >> SHIFT], 1);
        atomicAdd(&lh[c.z >> SHIFT], 1);
        atomicAdd(&lh[c.w >> SHIFT], 1);
    }
    __syncthreads();
    for (int i = threadIdx.x; i < NBIN; i += 256)
        cmat[b * NBIN + i] = lh[i];
}

// ---- cmat scan (bin-major virtual order) -> gbase ----

__global__ __launch_bounds__(256) void k_psumC(const int* __restrict__ cmat,
                                               int* __restrict__ bsum2) {
    int base = blockIdx.x * VTILE;
    int s = 0;
    for (int i = threadIdx.x; i < VTILE; i += 256) {
        int v = base + i;
        if (v < VTOT) {
            int bin = v / NBLK2, blk = v - bin * NBLK2;
            s += cmat[blk * NBIN + bin];
        }
    }
#pragma unroll
    for (int d = 32; d; d >>= 1) s += __shfl_down(s, d);
    __shared__ int wsum[4];
    if ((threadIdx.x & 63) == 0) wsum[threadIdx.x >> 6] = s;
    __syncthreads();
    if (threadIdx.x == 0) bsum2[blockIdx.x] = wsum[0] + wsum[1] + wsum[2] + wsum[3];
}

// tile-local scan + inline one-wave scan of the NVT tile sums
__global__ __launch_bounds__(256) void k_finC(const int* __restrict__ cmat,
                                              const int* __restrict__ bsum2,
                                              int* __restrict__ gbase) {
    __shared__ int ts[256];
    __shared__ int sboff;
    int t = threadIdx.x;
    if (t < 64) {                         // inline bscan (NVT<=64)
        int orig = (t < NVT) ? bsum2[t] : 0;
        int v = orig;
#pragma unroll
        for (int d = 1; d < 64; d <<= 1) {
            int u = __shfl_up(v, d);
            if (t >= d) v += u;
        }
        if (t == blockIdx.x) sboff = v - orig;
    }
    int s0 = blockIdx.x * VTILE + t * 8;
    int v[8];
    int sum = 0;
#pragma unroll
    for (int k = 0; k < 8; ++k) {
        int idx = s0 + k;
        if (idx < VTOT) {
            int bin = idx / NBLK2, blk = idx - bin * NBLK2;
            v[k] = cmat[blk * NBIN + bin];
        } else v[k] = 0;
        sum += v[k];
    }
    ts[t] = sum;
    __syncthreads();
    for (int d = 1; d < 256; d <<= 1) {
        int u = (t >= d) ? ts[t - d] : 0;
        __syncthreads();
        ts[t] += u;
        __syncthreads();
    }
    int run = sboff + ts[t] - sum;
#pragma unroll
    for (int k = 0; k < 8; ++k) {
        int idx = s0 + k;
        if (idx < VTOT) gbase[idx] = run;   // bin-major, coalesced
        run += v[k];
    }
}

// deterministic scatter into coarse bins (LDS cursors; int4 edge loads)
__global__ __launch_bounds__(256) void k_binD(const int* __restrict__ ei,
                                              const int* __restrict__ gbase,
                                              int* __restrict__ tmp) {
    __shared__ int lcur[NBIN];
    int b = blockIdx.x;
    for (int i = threadIdx.x; i < NBIN; i += 256)
        lcur[i] = gbase[i * NBLK2 + b];
    __syncthreads();
    int e0 = b * EPB2, e1 = min(e0 + EPB2, NE);
    const int4* src4 = (const int4*)ei;
    const int4* col4 = (const int4*)(ei + NE);
    for (int q = (e0 >> 2) + threadIdx.x; q < (e1 >> 2); q += 256) {
        int4 s = src4[q];
        int4 c = col4[q];
        int p0 = atomicAdd(&lcur[c.x >> SHIFT], 1);
        tmp[p0] = (s.x << SHIFT) | (c.x & (BINW - 1));
        int p1 = atomicAdd(&lcur[c.y >> SHIFT], 1);
        tmp[p1] = (s.y << SHIFT) | (c.y & (BINW - 1));
        int p2 = atomicAdd(&lcur[c.z >> SHIFT], 1);
        tmp[p2] = (s.z << SHIFT) | (c.z & (BINW - 1));
        int p3 = atomicAdd(&lcur[c.w >> SHIFT], 1);
        tmp[p3] = (s.w << SHIFT) | (c.w & (BINW - 1));
    }
}

// one block per bin: count (stashing slice in LDS) -> wave-shuffle scan ->
// place. One global pass over tmp; zero global atomics.
__global__ __launch_bounds__(256) void k_placeB(const int* __restrict__ gbase,
                                                const int* __restrict__ tmp,
                                                int* __restrict__ srt,
                                                int* __restrict__ off,
                                                float* __restrict__ dinv) {
    __shared__ int lcnt[BINW];
    __shared__ int lcur[BINW];
    __shared__ int stash[PCAP];
    __shared__ int wtot[4], wbase[4];
    int bin = blockIdx.x, t = threadIdx.x;
    int w = t >> 6, lane = t & 63;
    int s0 = gbase[bin * NBLK2];
    int s1 = (bin + 1 < NBIN) ? gbase[(bin + 1) * NBLK2] : NE;
    lcnt[t] = 0;
    __syncthreads();
    for (int i = s0 + t; i < s1; i += 256) {
        int v = tmp[i];
        int k = i - s0;
        if (k < PCAP) stash[k] = v;       // stash for pass 2
        atomicAdd(&lcnt[v & (BINW - 1)], 1);
    }
    __syncthreads();
    int cv = lcnt[t];
    int v = cv;                            // inclusive scan within wave
#pragma unroll
    for (int d = 1; d < 64; d <<= 1) {
        int u = __shfl_up(v, d);
        if (lane >= d) v += u;
    }
    if (lane == 63) wtot[w] = v;
    __syncthreads();
    if (t == 0) {
        int r = 0;
#pragma unroll
        for (int k = 0; k < 4; ++k) { wbase[k] = r; r += wtot[k]; }
    }
    __syncthreads();
    int base = s0 + wbase[w] + v - cv;     // exclusive node offset
    lcur[t] = base;
    int node = (bin << SHIFT) + t;
    if (node < NN) {
        off[node] = base;
        dinv[node] = rsqrtf(1.0f + (float)cv);   // deg incl. self-loop
        if (node == NN - 1) off[NN] = NE;
    }
    __syncthreads();
    for (int i = s0 + t; i < s1; i += 256) {
        int k = i - s0;
        int e = (k < PCAP) ? stash[k] : tmp[i];
        int pos = atomicAdd(&lcur[e & (BINW - 1)], 1);
        srt[pos] = e >> SHIFT;
    }
}

// h' = bf16( dinv * (x @ W^T) ), packed 2 channels/uint -> 64B rows.
__global__ __launch_bounds__(256) void k_linear(const float* __restrict__ x,
                                                const float* __restrict__ W,
                                                const float* __restrict__ dinv,
                                                unsigned* __restrict__ hu) {
    __shared__ float Ws[C][C + 1];
    __shared__ float xs[16][C];
    int t = threadIdx.x;
    for (int i = t; i < C * C; i += 256)
        Ws[i / C][i % C] = W[i];

    int node0 = blockIdx.x * 16;
#pragma unroll
    for (int i = t; i < 16 * C; i += 256) {
        int idx = node0 * C + i;     // coalesced load of 16 rows
        xs[i >> 5][i & 31] = (idx < NN * C) ? x[idx] : 0.0f;
    }
    __syncthreads();
    int lnode = t >> 4, m = t & 15;
    int node = node0 + lnode;
    if (node < NN) {
        float a0 = 0.0f, a1 = 0.0f;
#pragma unroll
        for (int k = 0; k < C; ++k) {
            float xv = xs[lnode][k];
            a0 += xv * Ws[2 * m][k];
            a1 += xv * Ws[2 * m + 1][k];
        }
        float d = dinv[node];
        hu[node * 16 + m] = bf16rne(a0 * d) | (bf16rne(a1 * d) << 16);
    }
}

// one 64-lane wave per node; 16-lane quarter-wave per edge row (64B = 1
// line), 4 edges/iter, 4x unrolled (4 rows in flight per slot-lane).
__global__ __launch_bounds__(256) void k_agg(const int* __restrict__ off,
                                             const int* __restrict__ srt,
                                             const unsigned* __restrict__ hu,
                                             const float* __restrict__ dinv,
                                             const float* __restrict__ b,
                                             float* __restrict__ out) {
    int n = (blockIdx.x * blockDim.x + threadIdx.x) >> 6;
    if (n >= NN) return;
    int lane = threadIdx.x & 63;
    int q = lane >> 4, m = lane & 15;    // slot q handles edges j%4==q
    int beg = off[n], end = off[n + 1];
    float sx = 0.0f, sy = 0.0f, sx2 = 0.0f, sy2 = 0.0f;
    int j = beg + q;
    for (; j + 12 < end; j += 16) {
        int r0 = srt[j], r1 = srt[j + 4], r2 = srt[j + 8], r3 = srt[j + 12];
        unsigned u0 = hu[r0 * 16 + m];
        unsigned u1 = hu[r1 * 16 + m];
        unsigned u2 = hu[r2 * 16 + m];
        unsigned u3 = hu[r3 * 16 + m];
        sx  += __uint_as_float(u0 << 16);
        sy  += __uint_as_float(u0 & 0xffff0000u);
        sx2 += __uint_as_float(u1 << 16);
        sy2 += __uint_as_float(u1 & 0xffff0000u);
        sx  += __uint_as_float(u2 << 16);
        sy  += __uint_as_float(u2 & 0xffff0000u);
        sx2 += __uint_as_float(u3 << 16);
        sy2 += __uint_as_float(u3 & 0xffff0000u);
    }
    for (; j < end; j += 4) {
        unsigned u = hu[srt[j] * 16 + m];
        sx += __uint_as_float(u << 16);
        sy += __uint_as_float(u & 0xffff0000u);
    }
    sx += sx2; sy += sy2;
    sx += __shfl_xor(sx, 16); sy += __shfl_xor(sy, 16);
    sx += __shfl_xor(sx, 32); sy += __shfl_xor(sy, 32);
    if (q == 0) {
        float dn = dinv[n];
        unsigned us = hu[n * 16 + m];    // self-loop row (pre-scaled)
        float ox = b[2 * m]     + dn * (sx + __uint_as_float(us << 16));
        float oy = b[2 * m + 1] + dn * (sy + __uint_as_float(us & 0xffff0000u));
        ((float2*)out)[n * 16 + m] = make_float2(ox, oy);
    }
}

// ---------------- launch ----------------

extern "C" void kernel_launch(void* const* d_in, const int* in_sizes, int n_in,
                              void* d_out, int out_size, void* d_ws, size_t ws_size,
                              hipStream_t stream) {
    const float* x  = (const float*)d_in[0];
    const int*   ei = (const int*)d_in[1];
    const float* W  = (const float*)d_in[2];
    const float* b  = (const float*)d_in[3];
    float* out = (float*)d_out;

    // ws (~21 MB of 256 MB pool) — no overlays, all buffers distinct
    char* ws = (char*)d_ws;
    size_t o = 0;
    int*      tmp  = (int*)(ws + o);      o += (size_t)NE * 4;        o = (o + 255) & ~(size_t)255;
    int*      srt  = (int*)(ws + o);      o += (size_t)NE * 4;        o = (o + 255) & ~(size_t)255;
    unsigned* hu   = (unsigned*)(ws + o); o += (size_t)NN * 16 * 4;   o = (o + 255) & ~(size_t)255;
    int*      cmat = (int*)(ws + o);      o += (size_t)VTOT * 4;      o = (o + 255) & ~(size_t)255;
    int*      gbase= (int*)(ws + o);      o += (size_t)VTOT * 4;      o = (o + 255) & ~(size_t)255;
    int*      off  = (int*)(ws + o);      o += (size_t)(NN + 1) * 4;  o = (o + 255) & ~(size_t)255;
    float*    dinv = (float*)(ws + o);    o += (size_t)NN * 4;        o = (o + 255) & ~(size_t)255;
    int*      bsum2= (int*)(ws + o);

    k_histB<<<NBLK2, 256, 0, stream>>>(ei, cmat);
    k_psumC<<<NVT, 256, 0, stream>>>(cmat, bsum2);
    k_finC<<<NVT, 256, 0, stream>>>(cmat, bsum2, gbase);
    k_binD<<<NBLK2, 256, 0, stream>>>(ei, gbase, tmp);
    k_placeB<<<NBIN, 256, 0, stream>>>(gbase, tmp, srt, off, dinv);
    k_linear<<<(NN + 15) / 16, 256, 0, stream>>>(x, W, dinv, hu);
    k_agg<<<(NN * 64 + 255) / 256, 256, 0, stream>>>(off, srt, hu, dinv, b, out);
}

// Round 13
// 162.356 us; speedup vs baseline: 2.8918x; 1.0182x over previous
//
#include <hip/hip_runtime.h>

#define NN 100000
#define NE 1600000
#define C 32

#define SHIFT 8
#define BINW 256                              // nodes per bin
#define NBIN ((NN + BINW - 1) / BINW)         // 391
#define EPB2 8192                             // edges per block (binning)
#define NBLK2 ((NE + EPB2 - 1) / EPB2)        // 196
#define VTOT (NBIN * NBLK2)                   // 76636 (bin-major cmat scan)
#define VTILE 2048
#define NVT ((VTOT + VTILE - 1) / VTILE)      // 38 (<=64: one-wave scan)
#define PCAP 5376                             // placeB LDS stash entries (20σ)

__device__ __forceinline__ unsigned bf16rne(float f) {
    unsigned u = __float_as_uint(f);
    return (u + 0x7fffu + ((u >> 16) & 1u)) >> 16;
}
__device__ __forceinline__ float blo(unsigned u) { return __uint_as_float(u << 16); }
__device__ __forceinline__ float bhi(unsigned u) { return __uint_as_float(u & 0xffff0000u); }

// ---------------- kernels ----------------

// per-block coarse-bin histogram (LDS only; int4 edge loads)
__global__ __launch_bounds__(256) void k_histB(const int* __restrict__ ei,
                                               int* __restrict__ cmat) {
    __shared__ int lh[NBIN];
    for (int i = threadIdx.x; i < NBIN; i += 256) lh[i] = 0;
    __syncthreads();
    int b = blockIdx.x;
    int e0 = b * EPB2, e1 = min(e0 + EPB2, NE);   // window always %4==0
    const int4* col4 = (const int4*)(ei + NE);
    for (int q = (e0 >> 2) + threadIdx.x; q < (e1 >> 2); q += 256) {
        int4 c = col4[q];
        atomicAdd(&lh[c.x >> SHIFT], 1);
        atomicAdd(&lh[c.y >> SHIFT], 1);
        atomicAdd(&lh[c.z >> SHIFT], 1);
        atomicAdd(&lh[c.w >> SHIFT], 1);
    }
    __syncthreads();
    for (int i = threadIdx.x; i < NBIN; i += 256)
        cmat[b * NBIN + i] = lh[i];
}

// ---- cmat scan (bin-major virtual order) -> gbase ----

__global__ __launch_bounds__(256) void k_psumC(const int* __restrict__ cmat,
                                               int* __restrict__ bsum2) {
    int base = blockIdx.x * VTILE;
    int s = 0;
    for (int i = threadIdx.x; i < VTILE; i += 256) {
        int v = base + i;
        if (v < VTOT) {
            int bin = v / NBLK2, blk = v - bin * NBLK2;
            s += cmat[blk * NBIN + bin];
        }
    }
#pragma unroll
    for (int d = 32; d; d >>= 1) s += __shfl_down(s, d);
    __shared__ int wsum[4];
    if ((threadIdx.x & 63) == 0) wsum[threadIdx.x >> 6] = s;
    __syncthreads();
    if (threadIdx.x == 0) bsum2[blockIdx.x] = wsum[0] + wsum[1] + wsum[2] + wsum[3];
}

// tile-local scan + inline one-wave scan of the NVT tile sums
__global__ __launch_bounds__(256) void k_finC(const int* __restrict__ cmat,
                                              const int* __restrict__ bsum2,
                                              int* __restrict__ gbase) {
    __shared__ int ts[256];
    __shared__ int sboff;
    int t = threadIdx.x;
    if (t < 64) {                         // inline bscan (NVT<=64)
        int orig = (t < NVT) ? bsum2[t] : 0;
        int v = orig;
#pragma unroll
        for (int d = 1; d < 64; d <<= 1) {
            int u = __shfl_up(v, d);
            if (t >= d) v += u;
        }
        if (t == blockIdx.x) sboff = v - orig;
    }
    int s0 = blockIdx.x * VTILE + t * 8;
    int v[8];
    int sum = 0;
#pragma unroll
    for (int k = 0; k < 8; ++k) {
        int idx = s0 + k;
        if (idx < VTOT) {
            int bin = idx / NBLK2, blk = idx - bin * NBLK2;
            v[k] = cmat[blk * NBIN + bin];
        } else v[k] = 0;
        sum += v[k];
    }
    ts[t] = sum;
    __syncthreads();
    for (int d = 1; d < 256; d <<= 1) {
        int u = (t >= d) ? ts[t - d] : 0;
        __syncthreads();
        ts[t] += u;
        __syncthreads();
    }
    int run = sboff + ts[t] - sum;
#pragma unroll
    for (int k = 0; k < 8; ++k) {
        int idx = s0 + k;
        if (idx < VTOT) gbase[idx] = run;   // bin-major, coalesced
        run += v[k];
    }
}

// deterministic scatter into coarse bins (LDS cursors; int4 edge loads)
__global__ __launch_bounds__(256) void k_binD(const int* __restrict__ ei,
                                              const int* __restrict__ gbase,
                                              int* __restrict__ tmp) {
    __shared__ int lcur[NBIN];
    int b = blockIdx.x;
    for (int i = threadIdx.x; i < NBIN; i += 256)
        lcur[i] = gbase[i * NBLK2 + b];
    __syncthreads();
    int e0 = b * EPB2, e1 = min(e0 + EPB2, NE);
    const int4* src4 = (const int4*)ei;
    const int4* col4 = (const int4*)(ei + NE);
    for (int q = (e0 >> 2) + threadIdx.x; q < (e1 >> 2); q += 256) {
        int4 s = src4[q];
        int4 c = col4[q];
        int p0 = atomicAdd(&lcur[c.x >> SHIFT], 1);
        tmp[p0] = (s.x << SHIFT) | (c.x & (BINW - 1));
        int p1 = atomicAdd(&lcur[c.y >> SHIFT], 1);
        tmp[p1] = (s.y << SHIFT) | (c.y & (BINW - 1));
        int p2 = atomicAdd(&lcur[c.z >> SHIFT], 1);
        tmp[p2] = (s.z << SHIFT) | (c.z & (BINW - 1));
        int p3 = atomicAdd(&lcur[c.w >> SHIFT], 1);
        tmp[p3] = (s.w << SHIFT) | (c.w & (BINW - 1));
    }
}

// one block per bin: count (stashing slice in LDS) -> wave-shuffle scan ->
// place. One global pass over tmp; zero global atomics.
__global__ __launch_bounds__(256) void k_placeB(const int* __restrict__ gbase,
                                                const int* __restrict__ tmp,
                                                int* __restrict__ srt,
                                                int* __restrict__ off,
                                                float* __restrict__ dinv) {
    __shared__ int lcnt[BINW];
    __shared__ int lcur[BINW];
    __shared__ int stash[PCAP];
    __shared__ int wtot[4], wbase[4];
    int bin = blockIdx.x, t = threadIdx.x;
    int w = t >> 6, lane = t & 63;
    int s0 = gbase[bin * NBLK2];
    int s1 = (bin + 1 < NBIN) ? gbase[(bin + 1) * NBLK2] : NE;
    lcnt[t] = 0;
    __syncthreads();
    for (int i = s0 + t; i < s1; i += 256) {
        int v = tmp[i];
        int k = i - s0;
        if (k < PCAP) stash[k] = v;       // stash for pass 2
        atomicAdd(&lcnt[v & (BINW - 1)], 1);
    }
    __syncthreads();
    int cv = lcnt[t];
    int v = cv;                            // inclusive scan within wave
#pragma unroll
    for (int d = 1; d < 64; d <<= 1) {
        int u = __shfl_up(v, d);
        if (lane >= d) v += u;
    }
    if (lane == 63) wtot[w] = v;
    __syncthreads();
    if (t == 0) {
        int r = 0;
#pragma unroll
        for (int k = 0; k < 4; ++k) { wbase[k] = r; r += wtot[k]; }
    }
    __syncthreads();
    int base = s0 + wbase[w] + v - cv;     // exclusive node offset
    lcur[t] = base;
    int node = (bin << SHIFT) + t;
    if (node < NN) {
        off[node] = base;
        dinv[node] = rsqrtf(1.0f + (float)cv);   // deg incl. self-loop
        if (node == NN - 1) off[NN] = NE;
    }
    __syncthreads();
    for (int i = s0 + t; i < s1; i += 256) {
        int k = i - s0;
        int e = (k < PCAP) ? stash[k] : tmp[i];
        int pos = atomicAdd(&lcur[e & (BINW - 1)], 1);
        srt[pos] = e >> SHIFT;
    }
}

// h' = bf16( dinv * (x @ W^T) ), packed 2 channels/uint -> 64B rows.
__global__ __launch_bounds__(256) void k_linear(const float* __restrict__ x,
                                                const float* __restrict__ W,
                                                const float* __restrict__ dinv,
                                                unsigned* __restrict__ hu) {
    __shared__ float Ws[C][C + 1];
    __shared__ float xs[16][C];
    int t = threadIdx.x;
    for (int i = t; i < C * C; i += 256)
        Ws[i / C][i % C] = W[i];

    int node0 = blockIdx.x * 16;
#pragma unroll
    for (int i = t; i < 16 * C; i += 256) {
        int idx = node0 * C + i;     // coalesced load of 16 rows
        xs[i >> 5][i & 31] = (idx < NN * C) ? x[idx] : 0.0f;
    }
    __syncthreads();
    int lnode = t >> 4, m = t & 15;
    int node = node0 + lnode;
    if (node < NN) {
        float a0 = 0.0f, a1 = 0.0f;
#pragma unroll
        for (int k = 0; k < C; ++k) {
            float xv = xs[lnode][k];
            a0 += xv * Ws[2 * m][k];
            a1 += xv * Ws[2 * m + 1][k];
        }
        float d = dinv[node];
        hu[node * 16 + m] = bf16rne(a0 * d) | (bf16rne(a1 * d) << 16);
    }
}

// one 64-lane wave per node; 8 slots x 8 lanes, uint2 (8B) per lane ->
// 8 edge rows in flight per load instr, 32 in the unrolled body.
__global__ __launch_bounds__(256) void k_agg(const int* __restrict__ off,
                                             const int* __restrict__ srt,
                                             const uint2* __restrict__ hu2,
                                             const float* __restrict__ dinv,
                                             const float* __restrict__ b,
                                             float* __restrict__ out) {
    int n = (blockIdx.x * blockDim.x + threadIdx.x) >> 6;
    if (n >= NN) return;
    int lane = threadIdx.x & 63;
    int q = lane >> 3, m = lane & 7;     // slot q, lane m -> channels 4m..4m+3
    int beg = off[n], end = off[n + 1];
    float s0 = 0.0f, s1 = 0.0f, s2 = 0.0f, s3 = 0.0f;
    int j = beg + q;
    for (; j + 24 < end; j += 32) {
        int r0 = srt[j], r1 = srt[j + 8], r2 = srt[j + 16], r3 = srt[j + 24];
        uint2 u0 = hu2[r0 * 8 + m];
        uint2 u1 = hu2[r1 * 8 + m];
        uint2 u2 = hu2[r2 * 8 + m];
        uint2 u3 = hu2[r3 * 8 + m];
        s0 += blo(u0.x); s1 += bhi(u0.x); s2 += blo(u0.y); s3 += bhi(u0.y);
        s0 += blo(u1.x); s1 += bhi(u1.x); s2 += blo(u1.y); s3 += bhi(u1.y);
        s0 += blo(u2.x); s1 += bhi(u2.x); s2 += blo(u2.y); s3 += bhi(u2.y);
        s0 += blo(u3.x); s1 += bhi(u3.x); s2 += blo(u3.y); s3 += bhi(u3.y);
    }
    for (; j < end; j += 8) {
        uint2 u = hu2[srt[j] * 8 + m];
        s0 += blo(u.x); s1 += bhi(u.x); s2 += blo(u.y); s3 += bhi(u.y);
    }
#pragma unroll
    for (int d = 8; d < 64; d <<= 1) {
        s0 += __shfl_xor(s0, d);
        s1 += __shfl_xor(s1, d);
        s2 += __shfl_xor(s2, d);
        s3 += __shfl_xor(s3, d);
    }
    if (q == 0) {
        float dn = dinv[n];
        uint2 us = hu2[n * 8 + m];       // self-loop row (pre-scaled)
        float4 bb = ((const float4*)b)[m];
        float o0 = bb.x + dn * (s0 + blo(us.x));
        float o1 = bb.y + dn * (s1 + bhi(us.x));
        float o2 = bb.z + dn * (s2 + blo(us.y));
        float o3 = bb.w + dn * (s3 + bhi(us.y));
        ((float4*)out)[n * 8 + m] = make_float4(o0, o1, o2, o3);
    }
}

// ---------------- launch ----------------

extern "C" void kernel_launch(void* const* d_in, const int* in_sizes, int n_in,
                              void* d_out, int out_size, void* d_ws, size_t ws_size,
                              hipStream_t stream) {
    const float* x  = (const float*)d_in[0];
    const int*   ei = (const int*)d_in[1];
    const float* W  = (const float*)d_in[2];
    const float* b  = (const float*)d_in[3];
    float* out = (float*)d_out;

    // ws (~21 MB of 256 MB pool) — no overlays, all buffers distinct
    char* ws = (char*)d_ws;
    size_t o = 0;
    int*      tmp  = (int*)(ws + o);      o += (size_t)NE * 4;        o = (o + 255) & ~(size_t)255;
    int*      srt  = (int*)(ws + o);      o += (size_t)NE * 4;        o = (o + 255) & ~(size_t)255;
    unsigned* hu   = (unsigned*)(ws + o); o += (size_t)NN * 16 * 4;   o = (o + 255) & ~(size_t)255;
    int*      cmat = (int*)(ws + o);      o += (size_t)VTOT * 4;      o = (o + 255) & ~(size_t)255;
    int*      gbase= (int*)(ws + o);      o += (size_t)VTOT * 4;      o = (o + 255) & ~(size_t)255;
    int*      off  = (int*)(ws + o);      o += (size_t)(NN + 1) * 4;  o = (o + 255) & ~(size_t)255;
    float*    dinv = (float*)(ws + o);    o += (size_t)NN * 4;        o = (o + 255) & ~(size_t)255;
    int*      bsum2= (int*)(ws + o);

    k_histB<<<NBLK2, 256, 0, stream>>>(ei, cmat);
    k_psumC<<<NVT, 256, 0, stream>>>(cmat, bsum2);
    k_finC<<<NVT, 256, 0, stream>>>(cmat, bsum2, gbase);
    k_binD<<<NBLK2, 256, 0, stream>>>(ei, gbase, tmp);
    k_placeB<<<NBIN, 256, 0, stream>>>(gbase, tmp, srt, off, dinv);
    k_linear<<<(NN + 15) / 16, 256, 0, stream>>>(x, W, dinv, hu);
    k_agg<<<(NN * 64 + 255) / 256, 256, 0, stream>>>(off, srt, (const uint2*)hu, dinv, b, out);
}